// Round 12
// baseline (196.607 us; speedup 1.0000x reference)
//
#include <hip/hip_runtime.h>
#include <hip/hip_bf16.h>

// MultiHeadSelfAttention  B=2, S=4096, D=512, H=8, dk=64
// R24 == R21 byte-identical (measured 180.3us, session best). Lock-in round:
// R23 showed even definition-order changes perturb co-compiled regalloc by
// ~8us (rule #19); R18/R20/R22 schedule variants all regressed. This file is
// the empirical optimum of the structure:
//  - attn: R16 T15 deferred-PV body + lgkm-only barriers (global prefetch
//    rides across the barrier), XOR-swizzled LDS (0 conflicts), XCD swizzle
//    (K/V L2-resident, FETCH 12MB), in-kernel normalize, bf16 Oc out.
//  - GEMMs: BK=64, XOR-swizzled LDS via source-swizzled gll16.
// kappa(m) = 32*(m>>5) + 8*((m>>2)&3) + 4*((m>>4)&1) + (m&3)  per 64-group,
// baked into V^T global layout so P packs in-register into PV A-frags.

#define DMODEL 512
#define SEQ    4096
#define NTOK   8192
#define LDQK   1024

// lgkm-only barrier: ds ops drained, global prefetch loads stay in flight.
#define LGKM_BARRIER() do { \
  asm volatile("s_waitcnt lgkmcnt(0)" ::: "memory"); \
  __builtin_amdgcn_s_barrier(); \
} while (0)

using f32x4 = __attribute__((ext_vector_type(4))) float;
using s16x8 = __attribute__((ext_vector_type(8))) short;
using u16x8 = __attribute__((ext_vector_type(8))) unsigned short;

static __device__ __forceinline__ unsigned short f2bf(float f) {
  union { float f; unsigned u; } v; v.f = f;
  unsigned r = v.u + 0x7fff + ((v.u >> 16) & 1);   // RNE
  return (unsigned short)(r >> 16);
}

static __device__ __forceinline__ unsigned pack_bf2(float lo, float hi) {
  __hip_bfloat162 t = __float22bfloat162_rn(make_float2(lo, hi));
  union { __hip_bfloat162 b; unsigned u; } c; c.b = t; return c.u;
}

// async global->LDS, 16B per lane; lds base wave-uniform, lane i -> base+16i.
static __device__ __forceinline__ void gll16(const void* g, void* l) {
  __builtin_amdgcn_global_load_lds(
      (const __attribute__((address_space(1))) unsigned int*)g,
      (__attribute__((address_space(3))) unsigned int*)l, 16, 0, 0);
}

// Fused prep: blocks 0..1023 cast x -> bf16; blocks 1024..1279 transpose one
// 64x64 tile of one W into Wall = [Wq'|Wk|Wv|Wo] (N-major), Wq scaled by c2.
__global__ void prep_kernel(const float* __restrict__ x,
                            const float* __restrict__ Wq,
                            const float* __restrict__ Wk,
                            const float* __restrict__ Wv,
                            const float* __restrict__ Wo,
                            unsigned short* __restrict__ xb,
                            unsigned short* __restrict__ Wall, float c2) {
  __shared__ float T[64][65];
  const int bx = blockIdx.x;
  if (bx < 1024) {
    for (int i = bx * 256 + threadIdx.x; i < NTOK * DMODEL / 4; i += 262144) {
      float4 v = ((const float4*)x)[i];
      ushort4 o;
      o.x = f2bf(v.x); o.y = f2bf(v.y); o.z = f2bf(v.z); o.w = f2bf(v.w);
      ((ushort4*)xb)[i] = o;
    }
    return;
  }
  const int t = bx - 1024;
  const int y = t >> 6, sub = t & 63;
  const float* W = (y == 0) ? Wq : (y == 1) ? Wk : (y == 2) ? Wv : Wo;
  const float scale = (y == 0) ? c2 : 1.0f;
  const int tk = (sub & 7) * 64;
  const int tn = (sub >> 3) * 64;
  const int r  = threadIdx.x >> 2;
  const int cq = threadIdx.x & 3;
#pragma unroll
  for (int i = 0; i < 4; ++i) {
    int c = (cq + 4 * i) * 4;
    float4 v = *(const float4*)&W[(size_t)(tk + r) * 512 + tn + c];
    T[r][c + 0] = v.x * scale; T[r][c + 1] = v.y * scale;
    T[r][c + 2] = v.z * scale; T[r][c + 3] = v.w * scale;
  }
  __syncthreads();
  const int n  = threadIdx.x >> 2;
  const int k0 = (threadIdx.x & 3) * 16;
#pragma unroll
  for (int j4 = 0; j4 < 4; ++j4) {
    ushort4 o;
    o.x = f2bf(T[k0 + j4 * 4 + 0][n]);
    o.y = f2bf(T[k0 + j4 * 4 + 1][n]);
    o.z = f2bf(T[k0 + j4 * 4 + 2][n]);
    o.w = f2bf(T[k0 + j4 * 4 + 3][n]);
    *(ushort4*)&Wall[(size_t)y * 262144 + (size_t)(tn + n) * 512 + tk + k0 + j4 * 4] = o;
  }
}

// Fused QK + V^T GEMM. grid (64, 12). BK=64, XOR-swizzled LDS (R19).
//  by 0..7 : QK block  — C[8192 x 1024] = xb @ [Wq'|Wk]^T, bf16 row-major.
//  by 8..11: V^T block — C[512 x 8192] = Wv_t @ xb^T, stored batched
//            [b][m=h*64+dk][s] with kappa-permuted s within 64-groups.
// LDS invariant: LDS byte (row*128 + c) holds tile byte (row, c^((row&7)<<4)).
// gll16 dest LINEAR; XOR baked into per-lane global source (involution).
__global__ __launch_bounds__(256, 3) void gemm_qkv(
    const unsigned short* __restrict__ xb,
    const unsigned short* __restrict__ Wall,
    unsigned short* __restrict__ QKb,
    unsigned short* __restrict__ Vtb)
{
  __shared__ unsigned short As[128 * 64];
  __shared__ unsigned short Bs[128 * 64];
  const int by = blockIdx.y;
  const bool vmode = (by >= 8);
  const unsigned short* A  = vmode ? (Wall + 2 * 262144) : xb;
  const unsigned short* Bt = vmode ? xb : Wall;
  const size_t bm = vmode ? (size_t)(by - 8) * 128 : (size_t)blockIdx.x * 128;
  const size_t bn = vmode ? (size_t)blockIdx.x * 128 : (size_t)by * 128;
  const int tid  = threadIdx.x;
  const int wave = tid >> 6, lane = tid & 63;
  const int q4 = lane >> 4, ln = lane & 15;
  const int wm = (wave >> 1) * 64, wn = (wave & 1) * 64;
  f32x4 acc[4][4] = {};

  const int rlo  = lane >> 3;                       // 0..7
  const int sbx  = ((lane & 7) << 4) ^ (rlo << 4);  // swizzled src byte col
  const int rswz = (ln & 7) << 4;                   // read-side swizzle

  // staging: wave w stages tile rows [w*32, w*32+32), 4 call sites x 8 rows.
  const char* Asb = (const char*)A  + (size_t)(bm + wave * 32 + rlo) * 1024 + sbx;
  const char* Bsb = (const char*)Bt + (size_t)(bn + wave * 32 + rlo) * 1024 + sbx;
  char* Adst = (char*)As + wave * 4096;
  char* Bdst = (char*)Bs + wave * 4096;

  for (int kt = 0; kt < 512; kt += 64) {
    __syncthreads();
#pragma unroll
    for (int j = 0; j < 4; ++j) {
      gll16(Asb + kt * 2 + j * 8192, Adst + j * 1024);
      gll16(Bsb + kt * 2 + j * 8192, Bdst + j * 1024);
    }
    __syncthreads();   // implies vmcnt(0): staged data visible
    s16x8 bfr[4][2];
#pragma unroll
    for (int ni = 0; ni < 4; ni++) {
      const char* bb = (char*)Bs + (wn + ni * 16 + ln) * 128;
      bfr[ni][0] = *(const s16x8*)(bb + ((q4 * 16)      ^ rswz));
      bfr[ni][1] = *(const s16x8*)(bb + ((q4 * 16 + 64) ^ rswz));
    }
#pragma unroll
    for (int mi = 0; mi < 4; mi++) {
      const char* ab = (char*)As + (wm + mi * 16 + ln) * 128;
      s16x8 af0 = *(const s16x8*)(ab + ((q4 * 16)      ^ rswz));
      s16x8 af1 = *(const s16x8*)(ab + ((q4 * 16 + 64) ^ rswz));
#pragma unroll
      for (int ni = 0; ni < 4; ni++) {
        acc[mi][ni] = __builtin_amdgcn_mfma_f32_16x16x32_bf16(
            af0, bfr[ni][0], acc[mi][ni], 0, 0, 0);
        acc[mi][ni] = __builtin_amdgcn_mfma_f32_16x16x32_bf16(
            af1, bfr[ni][1], acc[mi][ni], 0, 0, 0);
      }
    }
  }
#pragma unroll
  for (int mi = 0; mi < 4; mi++)
#pragma unroll
    for (int r = 0; r < 4; ++r) {
      size_t row = bm + wm + mi * 16 + q4 * 4 + r;
#pragma unroll
      for (int ni = 0; ni < 4; ni++) {
        size_t col = bn + wn + ni * 16 + ln;
        unsigned short hv = f2bf(acc[mi][ni][r]);
        if (!vmode) {
          QKb[row * 1024 + col] = hv;
        } else {
          int b = (int)(col >> 12), s = (int)(col & 4095);
          // kappa(s%64): slot holding key s for PV A-frag alignment
          int sp = (s & ~63) | (s & 32) | (((s >> 2) & 3) << 3) |
                   (((s >> 4) & 1) << 2) | (s & 3);
          Vtb[(size_t)b * 2097152 + row * 4096 + sp] = hv;
        }
      }
    }
}

// Flash-lite attention, no key-split, M=32 rows/wave, T15 pipelined (R16
// body), lgkm-only barriers (R21). grid (32 qt, 8 h, 2 b) = 512 blocks
// (2/CU); 4 waves x 32 q-rows = 128 q-rows/block; each block walks all 4096
// keys in 64 tiles. Iter t: QK(t); PV(t-1) from carried regs (interleaves
// with exp2/pack(t) VALU); stage t+1 (reg->LDS); prefetch t+2 (global->reg);
// LGKM_BARRIER (global prefetch loads ride across; ~200+cyc vmcnt-drain
// removed from every step). Normalizes by 1/l in-kernel, writes bf16 Oc.
// launch_bounds(256,2): do NOT raise (R9: (256,4) forced spills).
// LDS rows 64 shorts (128B), XOR-swizzled: byte_col ^= ((row&7)<<4) on both
// write and read (bijective per row; 0 bank conflicts measured R13-R20).
__global__ __launch_bounds__(256, 2) void attn_kernel(
    const unsigned short* __restrict__ QK,   // NTOK x 1024 [Q'|K]
    const unsigned short* __restrict__ Vt,   // [b*8+h][64 dk][4096 s-kappa]
    unsigned short* __restrict__ Oc)         // [8192][512] bf16, normalized
{
  // bijective XCD swizzle: XCD x gets lin x*64..x*64+63 (qt fastest) ->
  // each XCD covers exactly 2 (b,h) pairs, K/V 2MB resident in L2.
  const int bid = blockIdx.x + 32 * (blockIdx.y + 8 * blockIdx.z);
  const int lin = (bid & 7) * 64 + (bid >> 3);
  const int qt = lin & 31, bh = lin >> 5;
  const int h = bh & 7, b = bh >> 3;
  const int tid = threadIdx.x, wave = tid >> 6, lane = tid & 63;
  const int q4 = lane >> 4, ln = lane & 15;
  __shared__ unsigned short Ks[2][64 * 64];   // [buf][key][dk] swizzled
  __shared__ unsigned short Vs[2][64 * 64];   // [buf][dk][key-kappa] swizzled
  const size_t rowbase = (size_t)b * SEQ;
  const size_t qrow0   = (size_t)qt * 128 + wave * 32;
  const unsigned short* Kp  = QK + rowbase * LDQK + 512 + h * 64;
  const unsigned short* VTp = Vt + ((size_t)(b * 8 + h) * 64) * SEQ;

  s16x8 qf[2][2];   // B-frags: B[n=ln (q)][k=q4*8+j]
#pragma unroll
  for (int mf = 0; mf < 2; ++mf) {
    const unsigned short* q = QK + (rowbase + qrow0 + mf * 16 + ln) * LDQK + h * 64;
    qf[mf][0] = *(const s16x8*)(q + q4 * 8);
    qf[mf][1] = *(const s16x8*)(q + 32 + q4 * 8);
  }
  f32x4 o[2][4] = {};
  float lp[2] = {};                     // per-lane l partials (q = ln)

  const int srow = tid >> 2;            // 0..63
  const int c32  = (tid & 3) * 32;      // byte col: 0,32,64,96
  const int swz  = (srow & 7) << 4;
  const int wof0 = srow * 128 + ((c32 +  0) ^ swz);
  const int wof1 = srow * 128 + ((c32 + 16) ^ swz);
  const int rswz = (ln & 7) << 4;       // read-side swizzle (row&7 == ln&7)

  const unsigned short* kgp = Kp  + (size_t)srow * LDQK + (c32 >> 1);
  const unsigned short* vgp = VTp + (size_t)srow * SEQ + (c32 >> 1);

  // tile 0 -> regs -> buf0; prefetch tile 1 -> regs
  u16x8 kr  = *(const u16x8*)kgp;
  u16x8 kr2 = *(const u16x8*)(kgp + 8);
  u16x8 vr  = *(const u16x8*)vgp;
  u16x8 vr2 = *(const u16x8*)(vgp + 8);
  *(u16x8*)((char*)Ks[0] + wof0) = kr;
  *(u16x8*)((char*)Ks[0] + wof1) = kr2;
  *(u16x8*)((char*)Vs[0] + wof0) = vr;
  *(u16x8*)((char*)Vs[0] + wof1) = vr2;
  kgp += (size_t)64 * LDQK;  vgp += 64;
  kr  = *(const u16x8*)kgp;
  kr2 = *(const u16x8*)(kgp + 8);
  vr  = *(const u16x8*)vgp;
  vr2 = *(const u16x8*)(vgp + 8);
  LGKM_BARRIER();

  const f32x4 fz = {0.f, 0.f, 0.f, 0.f};   // shared zero acc (hoisted)

  s16x8 vfp[2][4];   // carried V frags of tile t-1 (PV pending)
  s16x8 pfp[2][2];   // carried P frags of tile t-1

  // ---- peeled t=0: QK(0), vf->vfp, softmax->pfp; stage 1; prefetch 2.
  {
    const char* Kc = (const char*)Ks[0];
    const char* Vc = (const char*)Vs[0];
    f32x4 s4[2][4];
#pragma unroll
    for (int ni = 0; ni < 4; ni++) {
      const char* kb = Kc + (ni * 16 + ln) * 128;
      s16x8 kf0 = *(const s16x8*)(kb + ((q4 * 16)      ^ rswz));
      s16x8 kf1 = *(const s16x8*)(kb + ((q4 * 16 + 64) ^ rswz));
      __builtin_amdgcn_s_setprio(1);
#pragma unroll
      for (int mf = 0; mf < 2; ++mf) {
        f32x4 acc0 = __builtin_amdgcn_mfma_f32_16x16x32_bf16(kf0, qf[mf][0], fz, 0, 0, 0);
        s4[mf][ni] = __builtin_amdgcn_mfma_f32_16x16x32_bf16(kf1, qf[mf][1], acc0, 0, 0, 0);
      }
      __builtin_amdgcn_s_setprio(0);
    }
#pragma unroll
    for (int ks = 0; ks < 2; ++ks)
#pragma unroll
      for (int ni = 0; ni < 4; ni++)
        vfp[ks][ni] = *(const s16x8*)(Vc + (ni * 16 + ln) * 128 +
                                      ((ks * 64 + q4 * 16) ^ rswz));
#pragma unroll
    for (int mf = 0; mf < 2; ++mf) {
      float e[4][4];
#pragma unroll
      for (int ni = 0; ni < 4; ni++)
#pragma unroll
        for (int r = 0; r < 4; ++r)
          e[ni][r] = __builtin_amdgcn_exp2f(s4[mf][ni][r]);
      float t0 = (e[0][0] + e[0][1]) + (e[0][2] + e[0][3]);
      float t1 = (e[1][0] + e[1][1]) + (e[1][2] + e[1][3]);
      float t2 = (e[2][0] + e[2][1]) + (e[2][2] + e[2][3]);
      float t3 = (e[3][0] + e[3][1]) + (e[3][2] + e[3][3]);
      lp[mf] += (t0 + t1) + (t2 + t3);
#pragma unroll
      for (int ks = 0; ks < 2; ++ks) {
        union { s16x8 v; unsigned u[4]; } pu;
        pu.u[0] = pack_bf2(e[2 * ks][0],     e[2 * ks][1]);
        pu.u[1] = pack_bf2(e[2 * ks][2],     e[2 * ks][3]);
        pu.u[2] = pack_bf2(e[2 * ks + 1][0], e[2 * ks + 1][1]);
        pu.u[3] = pack_bf2(e[2 * ks + 1][2], e[2 * ks + 1][3]);
        pfp[mf][ks] = pu.v;
      }
    }
    // stage tile 1 -> buf1; prefetch tile 2 -> regs
    char* Kn = (char*)Ks[1];
    char* Vn = (char*)Vs[1];
    *(u16x8*)(Kn + wof0) = kr;
    *(u16x8*)(Kn + wof1) = kr2;
    *(u16x8*)(Vn + wof0) = vr;
    *(u16x8*)(Vn + wof1) = vr2;
    kgp += (size_t)64 * LDQK;  vgp += 64;
    kr  = *(const u16x8*)kgp;
    kr2 = *(const u16x8*)(kgp + 8);
    vr  = *(const u16x8*)vgp;
    vr2 = *(const u16x8*)(vgp + 8);
    LGKM_BARRIER();
  }

  // ---- main loop t = 1..63: QK(t), PV(t-1), softmax(t), stage(t+1).
  // unroll 2 so the vfp/pfp rotate is killed by copy-prop.
#pragma unroll 2
  for (int t = 1; t < 64; ++t) {
    const int cur = t & 1;
    const char* Kc = (const char*)Ks[cur];
    const char* Vc = (const char*)Vs[cur];

    // S^T(t) = K Q'^T
    f32x4 s4[2][4];
#pragma unroll
    for (int ni = 0; ni < 4; ni++) {
      const char* kb = Kc + (ni * 16 + ln) * 128;
      s16x8 kf0 = *(const s16x8*)(kb + ((q4 * 16)      ^ rswz));
      s16x8 kf1 = *(const s16x8*)(kb + ((q4 * 16 + 64) ^ rswz));
      __builtin_amdgcn_s_setprio(1);
#pragma unroll
      for (int mf = 0; mf < 2; ++mf) {
        f32x4 acc0 = __builtin_amdgcn_mfma_f32_16x16x32_bf16(kf0, qf[mf][0], fz, 0, 0, 0);
        s4[mf][ni] = __builtin_amdgcn_mfma_f32_16x16x32_bf16(kf1, qf[mf][1], acc0, 0, 0, 0);
      }
      __builtin_amdgcn_s_setprio(0);
    }

    // O += P(t-1) V(t-1) — register-only; independent of s4(t), so the
    // scheduler interleaves these MFMAs with the exp2/pack VALU below.
#pragma unroll
    for (int ks = 0; ks < 2; ++ks)
#pragma unroll
      for (int ni = 0; ni < 4; ni++)
#pragma unroll
        for (int mf = 0; mf < 2; ++mf)
          o[mf][ni] = __builtin_amdgcn_mfma_f32_16x16x32_bf16(pfp[mf][ks], vfp[ks][ni], o[mf][ni], 0, 0, 0);

    // vf(t) from LDS (independent of exp2 chain)
    s16x8 vfc[2][4];
#pragma unroll
    for (int ks = 0; ks < 2; ++ks)
#pragma unroll
      for (int ni = 0; ni < 4; ni++)
        vfc[ks][ni] = *(const s16x8*)(Vc + (ni * 16 + ln) * 128 +
                                      ((ks * 64 + q4 * 16) ^ rswz));

    // p(t) = exp2(s^T): pack into PV A-frags (kappa-aligned).
    s16x8 pfc[2][2];
#pragma unroll
    for (int mf = 0; mf < 2; ++mf) {
      float e[4][4];
#pragma unroll
      for (int ni = 0; ni < 4; ni++)
#pragma unroll
        for (int r = 0; r < 4; ++r)
          e[ni][r] = __builtin_amdgcn_exp2f(s4[mf][ni][r]);
      float t0 = (e[0][0] + e[0][1]) + (e[0][2] + e[0][3]);
      float t1 = (e[1][0] + e[1][1]) + (e[1][2] + e[1][3]);
      float t2 = (e[2][0] + e[2][1]) + (e[2][2] + e[2][3]);
      float t3 = (e[3][0] + e[3][1]) + (e[3][2] + e[3][3]);
      lp[mf] += (t0 + t1) + (t2 + t3);
#pragma unroll
      for (int ks = 0; ks < 2; ++ks) {
        union { s16x8 v; unsigned u[4]; } pu;
        pu.u[0] = pack_bf2(e[2 * ks][0],     e[2 * ks][1]);
        pu.u[1] = pack_bf2(e[2 * ks][2],     e[2 * ks][3]);
        pu.u[2] = pack_bf2(e[2 * ks + 1][0], e[2 * ks + 1][1]);
        pu.u[3] = pack_bf2(e[2 * ks + 1][2], e[2 * ks + 1][3]);
        pfc[mf][ks] = pu.v;
      }
    }

    // stage tile t+1 into other buffer; prefetch tile t+2
    if (t + 1 < 64) {
      char* Kn = (char*)Ks[cur ^ 1];
      char* Vn = (char*)Vs[cur ^ 1];
      *(u16x8*)(Kn + wof0) = kr;
      *(u16x8*)(Kn + wof1) = kr2;
      *(u16x8*)(Vn + wof0) = vr;
      *(u16x8*)(Vn + wof1) = vr2;
      if (t + 2 < 64) {
        kgp += (size_t)64 * LDQK;  vgp += 64;
        kr  = *(const u16x8*)kgp;
        kr2 = *(const u16x8*)(kgp + 8);
        vr  = *(const u16x8*)vgp;
        vr2 = *(const u16x8*)(vgp + 8);
      }
    }

    // rotate carried state (renamed away by the unroll-2 copy-prop)
#pragma unroll
    for (int ks = 0; ks < 2; ++ks)
#pragma unroll
      for (int ni = 0; ni < 4; ni++)
        vfp[ks][ni] = vfc[ks][ni];
#pragma unroll
    for (int mf = 0; mf < 2; ++mf)
#pragma unroll
      for (int ks = 0; ks < 2; ++ks)
        pfp[mf][ks] = pfc[mf][ks];

    // ds writes/reads drained; t+2 global prefetch rides across the barrier.
    LGKM_BARRIER();
  }

  // ---- epilogue: PV(63)
  __builtin_amdgcn_s_setprio(1);
#pragma unroll
  for (int ks = 0; ks < 2; ++ks)
#pragma unroll
    for (int ni = 0; ni < 4; ni++)
#pragma unroll
      for (int mf = 0; mf < 2; ++mf)
        o[mf][ni] = __builtin_amdgcn_mfma_f32_16x16x32_bf16(pfp[mf][ks], vfp[ks][ni], o[mf][ni], 0, 0, 0);
  __builtin_amdgcn_s_setprio(0);

  // l: sum the 4 q4-replicas; after xor 16+32 every lane holds full l for
  // its ln. Normalize in-kernel, write bf16.
#pragma unroll
  for (int mf = 0; mf < 2; ++mf) {
    float l = lp[mf];
    l += __shfl_xor(l, 16, 64);
    l += __shfl_xor(l, 32, 64);
    const float inv = 1.0f / l;
#pragma unroll
    for (int r = 0; r < 4; ++r) {
      const float nv = __shfl(inv, q4 * 4 + r, 64);   // l for q-row q4*4+r
      const size_t row = rowbase + qrow0 + mf * 16 + q4 * 4 + r;
#pragma unroll
      for (int ni = 0; ni < 4; ni++)
        Oc[row * 512 + h * 64 + ni * 16 + ln] = f2bf(o[mf][ni][r] * nv);
    }
  }
}

// out = Oc @ Wo^T : M=8192 N=512 K=512, tile 128x64, BK=64, swizzled (R19).
__global__ __launch_bounds__(256, 3) void gemm_out(
    const unsigned short* __restrict__ A,
    const unsigned short* __restrict__ Bt,
    float* __restrict__ C)
{
  __shared__ unsigned short As[128 * 64];
  __shared__ unsigned short Bs[64 * 64];
  const int tid  = threadIdx.x;
  const int wave = tid >> 6, lane = tid & 63;
  const int q4 = lane >> 4, ln = lane & 15;
  const size_t bm = (size_t)blockIdx.x * 128;
  const size_t bn = (size_t)blockIdx.y * 64;
  const int wm = (wave >> 1) * 64, wn = (wave & 1) * 32;
  f32x4 acc[4][2] = {};

  const int rlo  = lane >> 3;
  const int sbx  = ((lane & 7) << 4) ^ (rlo << 4);
  const int rswz = (ln & 7) << 4;

  const char* Asb = (const char*)A  + (size_t)(bm + wave * 32 + rlo) * 1024 + sbx;
  const char* Bsb = (const char*)Bt + (size_t)(bn + wave * 16 + rlo) * 1024 + sbx;
  char* Adst = (char*)As + wave * 4096;
  char* Bdst = (char*)Bs + wave * 2048;

  for (int kt = 0; kt < 512; kt += 64) {
    __syncthreads();
#pragma unroll
    for (int j = 0; j < 4; ++j)
      gll16(Asb + kt * 2 + j * 8192, Adst + j * 1024);
#pragma unroll
    for (int j = 0; j < 2; ++j)
      gll16(Bsb + kt * 2 + j * 8192, Bdst + j * 1024);
    __syncthreads();   // implies vmcnt(0): staged data visible
    s16x8 bfr[2][2];
#pragma unroll
    for (int ni = 0; ni < 2; ni++) {
      const char* bb = (char*)Bs + (wn + ni * 16 + ln) * 128;
      bfr[ni][0] = *(const s16x8*)(bb + ((q4 * 16)      ^ rswz));
      bfr[ni][1] = *(const s16x8*)(bb + ((q4 * 16 + 64) ^ rswz));
    }
#pragma unroll
    for (int mi = 0; mi < 4; mi++) {
      const char* ab = (char*)As + (wm + mi * 16 + ln) * 128;
      s16x8 af0 = *(const s16x8*)(ab + ((q4 * 16)      ^ rswz));
      s16x8 af1 = *(const s16x8*)(ab + ((q4 * 16 + 64) ^ rswz));
#pragma unroll
      for (int ni = 0; ni < 2; ni++) {
        acc[mi][ni] = __builtin_amdgcn_mfma_f32_16x16x32_bf16(
            af0, bfr[ni][0], acc[mi][ni], 0, 0, 0);
        acc[mi][ni] = __builtin_amdgcn_mfma_f32_16x16x32_bf16(
            af1, bfr[ni][1], acc[mi][ni], 0, 0, 0);
      }
    }
  }
#pragma unroll
  for (int mi = 0; mi < 4; mi++)
#pragma unroll
    for (int r = 0; r < 4; ++r) {
      size_t row = bm + wm + mi * 16 + q4 * 4 + r;
#pragma unroll
      for (int ni = 0; ni < 2; ni++)
        C[row * 512 + bn + wn + ni * 16 + ln] = acc[mi][ni][r];
    }
}

extern "C" void kernel_launch(void* const* d_in, const int* in_sizes, int n_in,
                              void* d_out, int out_size, void* d_ws, size_t ws_size,
                              hipStream_t stream) {
  const float* x  = (const float*)d_in[0];
  const float* Wq = (const float*)d_in[1];
  const float* Wk = (const float*)d_in[2];
  const float* Wv = (const float*)d_in[3];
  const float* Wo = (const float*)d_in[4];

  char* ws = (char*)d_ws;
  unsigned short* xb    = (unsigned short*)(ws);              //  8,388,608
  unsigned short* Wall  = (unsigned short*)(ws + 8388608);    //  2,097,152
  unsigned short* QKb   = (unsigned short*)(ws + 10485760);   // 16,777,216
  unsigned short* Vtb   = (unsigned short*)(ws + 27262976);   //  8,388,608
  unsigned short* Oc    = (unsigned short*)(ws + 35651584);   //  8,388,608

  const float C2 = 0.125f * 1.44269504088896f;  // 1/sqrt(64) * log2(e)

  hipLaunchKernelGGL(prep_kernel, dim3(1280), dim3(256), 0, stream,
                     x, Wq, Wk, Wv, Wo, xb, Wall, C2);
  hipLaunchKernelGGL(gemm_qkv, dim3(64, 12), dim3(256), 0, stream,
                     xb, Wall, QKb, Vtb);
  hipLaunchKernelGGL(attn_kernel, dim3(32, 8, 2), dim3(256), 0, stream,
                     QKb, Vtb, Oc);
  hipLaunchKernelGGL(gemm_out, dim3(64, 8), dim3(256), 0, stream,
                     Oc, Wall + 3 * 262144, (float*)d_out);
}

// Round 13
// 179.132 us; speedup vs baseline: 1.0976x; 1.0976x over previous
//
#include <hip/hip_runtime.h>
#include <hip/hip_bf16.h>

// MultiHeadSelfAttention  B=2, S=4096, D=512, H=8, dk=64
// R25: clean single-variable A/B on the R21 base (R24 proved total-dur noise
// ~±16us; only per-dispatch attn time + counters are trustworthy).
// Change vs R21 (attn only): l accumulated via MFMA-by-ones alongside the
// deferred PV (ol[mf] += mfma(pfp, ones)) instead of ~30 VALU tree-adds/wave
// + 12 end shuffles. Arithmetic: saves ~480 VALU cyc/CU/step, costs ~155
// MFMA cyc; verified numerically in R17 (absmax identical — l sums the same
// bf16 P used for O; D-layout lands l on each lane's own output rows).
// All else byte-identical to R21: T15 deferred-PV body, lgkm-only barriers,
// XOR-swizzled LDS (0 conflicts), XCD swizzle (FETCH 12MB), BK=64 GEMMs.
// kappa(m) = 32*(m>>5) + 8*((m>>2)&3) + 4*((m>>4)&1) + (m&3)  per 64-group,
// baked into V^T global layout so P packs in-register into PV A-frags.

#define DMODEL 512
#define SEQ    4096
#define NTOK   8192
#define LDQK   1024

// lgkm-only barrier: ds ops drained, global prefetch loads stay in flight.
#define LGKM_BARRIER() do { \
  asm volatile("s_waitcnt lgkmcnt(0)" ::: "memory"); \
  __builtin_amdgcn_s_barrier(); \
} while (0)

using f32x4 = __attribute__((ext_vector_type(4))) float;
using s16x8 = __attribute__((ext_vector_type(8))) short;
using u16x8 = __attribute__((ext_vector_type(8))) unsigned short;

static __device__ __forceinline__ unsigned short f2bf(float f) {
  union { float f; unsigned u; } v; v.f = f;
  unsigned r = v.u + 0x7fff + ((v.u >> 16) & 1);   // RNE
  return (unsigned short)(r >> 16);
}

static __device__ __forceinline__ unsigned pack_bf2(float lo, float hi) {
  __hip_bfloat162 t = __float22bfloat162_rn(make_float2(lo, hi));
  union { __hip_bfloat162 b; unsigned u; } c; c.b = t; return c.u;
}

// async global->LDS, 16B per lane; lds base wave-uniform, lane i -> base+16i.
static __device__ __forceinline__ void gll16(const void* g, void* l) {
  __builtin_amdgcn_global_load_lds(
      (const __attribute__((address_space(1))) unsigned int*)g,
      (__attribute__((address_space(3))) unsigned int*)l, 16, 0, 0);
}

// Fused prep: blocks 0..1023 cast x -> bf16; blocks 1024..1279 transpose one
// 64x64 tile of one W into Wall = [Wq'|Wk|Wv|Wo] (N-major), Wq scaled by c2.
__global__ void prep_kernel(const float* __restrict__ x,
                            const float* __restrict__ Wq,
                            const float* __restrict__ Wk,
                            const float* __restrict__ Wv,
                            const float* __restrict__ Wo,
                            unsigned short* __restrict__ xb,
                            unsigned short* __restrict__ Wall, float c2) {
  __shared__ float T[64][65];
  const int bx = blockIdx.x;
  if (bx < 1024) {
    for (int i = bx * 256 + threadIdx.x; i < NTOK * DMODEL / 4; i += 262144) {
      float4 v = ((const float4*)x)[i];
      ushort4 o;
      o.x = f2bf(v.x); o.y = f2bf(v.y); o.z = f2bf(v.z); o.w = f2bf(v.w);
      ((ushort4*)xb)[i] = o;
    }
    return;
  }
  const int t = bx - 1024;
  const int y = t >> 6, sub = t & 63;
  const float* W = (y == 0) ? Wq : (y == 1) ? Wk : (y == 2) ? Wv : Wo;
  const float scale = (y == 0) ? c2 : 1.0f;
  const int tk = (sub & 7) * 64;
  const int tn = (sub >> 3) * 64;
  const int r  = threadIdx.x >> 2;
  const int cq = threadIdx.x & 3;
#pragma unroll
  for (int i = 0; i < 4; ++i) {
    int c = (cq + 4 * i) * 4;
    float4 v = *(const float4*)&W[(size_t)(tk + r) * 512 + tn + c];
    T[r][c + 0] = v.x * scale; T[r][c + 1] = v.y * scale;
    T[r][c + 2] = v.z * scale; T[r][c + 3] = v.w * scale;
  }
  __syncthreads();
  const int n  = threadIdx.x >> 2;
  const int k0 = (threadIdx.x & 3) * 16;
#pragma unroll
  for (int j4 = 0; j4 < 4; ++j4) {
    ushort4 o;
    o.x = f2bf(T[k0 + j4 * 4 + 0][n]);
    o.y = f2bf(T[k0 + j4 * 4 + 1][n]);
    o.z = f2bf(T[k0 + j4 * 4 + 2][n]);
    o.w = f2bf(T[k0 + j4 * 4 + 3][n]);
    *(ushort4*)&Wall[(size_t)y * 262144 + (size_t)(tn + n) * 512 + tk + k0 + j4 * 4] = o;
  }
}

// Fused QK + V^T GEMM. grid (64, 12). BK=64, XOR-swizzled LDS (R19).
//  by 0..7 : QK block  — C[8192 x 1024] = xb @ [Wq'|Wk]^T, bf16 row-major.
//  by 8..11: V^T block — C[512 x 8192] = Wv_t @ xb^T, stored batched
//            [b][m=h*64+dk][s] with kappa-permuted s within 64-groups.
// LDS invariant: LDS byte (row*128 + c) holds tile byte (row, c^((row&7)<<4)).
// gll16 dest LINEAR; XOR baked into per-lane global source (involution).
__global__ __launch_bounds__(256, 3) void gemm_qkv(
    const unsigned short* __restrict__ xb,
    const unsigned short* __restrict__ Wall,
    unsigned short* __restrict__ QKb,
    unsigned short* __restrict__ Vtb)
{
  __shared__ unsigned short As[128 * 64];
  __shared__ unsigned short Bs[128 * 64];
  const int by = blockIdx.y;
  const bool vmode = (by >= 8);
  const unsigned short* A  = vmode ? (Wall + 2 * 262144) : xb;
  const unsigned short* Bt = vmode ? xb : Wall;
  const size_t bm = vmode ? (size_t)(by - 8) * 128 : (size_t)blockIdx.x * 128;
  const size_t bn = vmode ? (size_t)blockIdx.x * 128 : (size_t)by * 128;
  const int tid  = threadIdx.x;
  const int wave = tid >> 6, lane = tid & 63;
  const int q4 = lane >> 4, ln = lane & 15;
  const int wm = (wave >> 1) * 64, wn = (wave & 1) * 64;
  f32x4 acc[4][4] = {};

  const int rlo  = lane >> 3;                       // 0..7
  const int sbx  = ((lane & 7) << 4) ^ (rlo << 4);  // swizzled src byte col
  const int rswz = (ln & 7) << 4;                   // read-side swizzle

  // staging: wave w stages tile rows [w*32, w*32+32), 4 call sites x 8 rows.
  const char* Asb = (const char*)A  + (size_t)(bm + wave * 32 + rlo) * 1024 + sbx;
  const char* Bsb = (const char*)Bt + (size_t)(bn + wave * 32 + rlo) * 1024 + sbx;
  char* Adst = (char*)As + wave * 4096;
  char* Bdst = (char*)Bs + wave * 4096;

  for (int kt = 0; kt < 512; kt += 64) {
    __syncthreads();
#pragma unroll
    for (int j = 0; j < 4; ++j) {
      gll16(Asb + kt * 2 + j * 8192, Adst + j * 1024);
      gll16(Bsb + kt * 2 + j * 8192, Bdst + j * 1024);
    }
    __syncthreads();   // implies vmcnt(0): staged data visible
    s16x8 bfr[4][2];
#pragma unroll
    for (int ni = 0; ni < 4; ni++) {
      const char* bb = (char*)Bs + (wn + ni * 16 + ln) * 128;
      bfr[ni][0] = *(const s16x8*)(bb + ((q4 * 16)      ^ rswz));
      bfr[ni][1] = *(const s16x8*)(bb + ((q4 * 16 + 64) ^ rswz));
    }
#pragma unroll
    for (int mi = 0; mi < 4; mi++) {
      const char* ab = (char*)As + (wm + mi * 16 + ln) * 128;
      s16x8 af0 = *(const s16x8*)(ab + ((q4 * 16)      ^ rswz));
      s16x8 af1 = *(const s16x8*)(ab + ((q4 * 16 + 64) ^ rswz));
#pragma unroll
      for (int ni = 0; ni < 4; ni++) {
        acc[mi][ni] = __builtin_amdgcn_mfma_f32_16x16x32_bf16(
            af0, bfr[ni][0], acc[mi][ni], 0, 0, 0);
        acc[mi][ni] = __builtin_amdgcn_mfma_f32_16x16x32_bf16(
            af1, bfr[ni][1], acc[mi][ni], 0, 0, 0);
      }
    }
  }
#pragma unroll
  for (int mi = 0; mi < 4; mi++)
#pragma unroll
    for (int r = 0; r < 4; ++r) {
      size_t row = bm + wm + mi * 16 + q4 * 4 + r;
#pragma unroll
      for (int ni = 0; ni < 4; ni++) {
        size_t col = bn + wn + ni * 16 + ln;
        unsigned short hv = f2bf(acc[mi][ni][r]);
        if (!vmode) {
          QKb[row * 1024 + col] = hv;
        } else {
          int b = (int)(col >> 12), s = (int)(col & 4095);
          // kappa(s%64): slot holding key s for PV A-frag alignment
          int sp = (s & ~63) | (s & 32) | (((s >> 2) & 3) << 3) |
                   (((s >> 4) & 1) << 2) | (s & 3);
          Vtb[(size_t)b * 2097152 + row * 4096 + sp] = hv;
        }
      }
    }
}

// Flash-lite attention, no key-split, M=32 rows/wave, T15 pipelined (R16
// body), lgkm-only barriers (R21), MFMA-ones l accumulation (R25).
// grid (32 qt, 8 h, 2 b) = 512 blocks (2/CU); 4 waves x 32 q-rows = 128
// q-rows/block; each block walks all 4096 keys in 64 tiles. Iter t: QK(t);
// PV(t-1) + l(t-1) from carried regs (interleave with exp2/pack(t) VALU);
// stage t+1 (reg->LDS); prefetch t+2 (global->reg); LGKM_BARRIER.
// Normalizes by 1/l in-kernel (l on each lane's own output rows via the
// MFMA D-layout — no cross-lane traffic), writes bf16 Oc.
// launch_bounds(256,2): do NOT raise (R9: spills). Do NOT double prefetch
// depth (R22: 107MB scratch).
// LDS rows 64 shorts (128B), XOR-swizzled: byte_col ^= ((row&7)<<4) on both
// write and read (bijective per row; 0 bank conflicts measured R13-R24).
__global__ __launch_bounds__(256, 2) void attn_kernel(
    const unsigned short* __restrict__ QK,   // NTOK x 1024 [Q'|K]
    const unsigned short* __restrict__ Vt,   // [b*8+h][64 dk][4096 s-kappa]
    unsigned short* __restrict__ Oc)         // [8192][512] bf16, normalized
{
  // bijective XCD swizzle: XCD x gets lin x*64..x*64+63 (qt fastest) ->
  // each XCD covers exactly 2 (b,h) pairs, K/V 2MB resident in L2.
  const int bid = blockIdx.x + 32 * (blockIdx.y + 8 * blockIdx.z);
  const int lin = (bid & 7) * 64 + (bid >> 3);
  const int qt = lin & 31, bh = lin >> 5;
  const int h = bh & 7, b = bh >> 3;
  const int tid = threadIdx.x, wave = tid >> 6, lane = tid & 63;
  const int q4 = lane >> 4, ln = lane & 15;
  __shared__ unsigned short Ks[2][64 * 64];   // [buf][key][dk] swizzled
  __shared__ unsigned short Vs[2][64 * 64];   // [buf][dk][key-kappa] swizzled
  const size_t rowbase = (size_t)b * SEQ;
  const size_t qrow0   = (size_t)qt * 128 + wave * 32;
  const unsigned short* Kp  = QK + rowbase * LDQK + 512 + h * 64;
  const unsigned short* VTp = Vt + ((size_t)(b * 8 + h) * 64) * SEQ;

  s16x8 qf[2][2];   // B-frags: B[n=ln (q)][k=q4*8+j]
#pragma unroll
  for (int mf = 0; mf < 2; ++mf) {
    const unsigned short* q = QK + (rowbase + qrow0 + mf * 16 + ln) * LDQK + h * 64;
    qf[mf][0] = *(const s16x8*)(q + q4 * 8);
    qf[mf][1] = *(const s16x8*)(q + 32 + q4 * 8);
  }
  f32x4 o[2][4] = {};
  f32x4 ol[2]   = {};                   // l accum (MFMA-ones): ol[mf][r] =
                                        // l for q-row q4*4+r (all ln equal)
  s16x8 onesf;                          // bf16 1.0 B-frag
#pragma unroll
  for (int j = 0; j < 8; ++j) onesf[j] = (short)0x3F80;

  const int srow = tid >> 2;            // 0..63
  const int c32  = (tid & 3) * 32;      // byte col: 0,32,64,96
  const int swz  = (srow & 7) << 4;
  const int wof0 = srow * 128 + ((c32 +  0) ^ swz);
  const int wof1 = srow * 128 + ((c32 + 16) ^ swz);
  const int rswz = (ln & 7) << 4;       // read-side swizzle (row&7 == ln&7)

  const unsigned short* kgp = Kp  + (size_t)srow * LDQK + (c32 >> 1);
  const unsigned short* vgp = VTp + (size_t)srow * SEQ + (c32 >> 1);

  // tile 0 -> regs -> buf0; prefetch tile 1 -> regs
  u16x8 kr  = *(const u16x8*)kgp;
  u16x8 kr2 = *(const u16x8*)(kgp + 8);
  u16x8 vr  = *(const u16x8*)vgp;
  u16x8 vr2 = *(const u16x8*)(vgp + 8);
  *(u16x8*)((char*)Ks[0] + wof0) = kr;
  *(u16x8*)((char*)Ks[0] + wof1) = kr2;
  *(u16x8*)((char*)Vs[0] + wof0) = vr;
  *(u16x8*)((char*)Vs[0] + wof1) = vr2;
  kgp += (size_t)64 * LDQK;  vgp += 64;
  kr  = *(const u16x8*)kgp;
  kr2 = *(const u16x8*)(kgp + 8);
  vr  = *(const u16x8*)vgp;
  vr2 = *(const u16x8*)(vgp + 8);
  LGKM_BARRIER();

  const f32x4 fz = {0.f, 0.f, 0.f, 0.f};   // shared zero acc (hoisted)

  s16x8 vfp[2][4];   // carried V frags of tile t-1 (PV pending)
  s16x8 pfp[2][2];   // carried P frags of tile t-1

  // ---- peeled t=0: QK(0), vf->vfp, softmax->pfp; stage 1; prefetch 2.
  {
    const char* Kc = (const char*)Ks[0];
    const char* Vc = (const char*)Vs[0];
    f32x4 s4[2][4];
#pragma unroll
    for (int ni = 0; ni < 4; ni++) {
      const char* kb = Kc + (ni * 16 + ln) * 128;
      s16x8 kf0 = *(const s16x8*)(kb + ((q4 * 16)      ^ rswz));
      s16x8 kf1 = *(const s16x8*)(kb + ((q4 * 16 + 64) ^ rswz));
      __builtin_amdgcn_s_setprio(1);
#pragma unroll
      for (int mf = 0; mf < 2; ++mf) {
        f32x4 acc0 = __builtin_amdgcn_mfma_f32_16x16x32_bf16(kf0, qf[mf][0], fz, 0, 0, 0);
        s4[mf][ni] = __builtin_amdgcn_mfma_f32_16x16x32_bf16(kf1, qf[mf][1], acc0, 0, 0, 0);
      }
      __builtin_amdgcn_s_setprio(0);
    }
#pragma unroll
    for (int ks = 0; ks < 2; ++ks)
#pragma unroll
      for (int ni = 0; ni < 4; ni++)
        vfp[ks][ni] = *(const s16x8*)(Vc + (ni * 16 + ln) * 128 +
                                      ((ks * 64 + q4 * 16) ^ rswz));
#pragma unroll
    for (int mf = 0; mf < 2; ++mf) {
      float e[4][4];
#pragma unroll
      for (int ni = 0; ni < 4; ni++)
#pragma unroll
        for (int r = 0; r < 4; ++r)
          e[ni][r] = __builtin_amdgcn_exp2f(s4[mf][ni][r]);
#pragma unroll
      for (int ks = 0; ks < 2; ++ks) {
        union { s16x8 v; unsigned u[4]; } pu;
        pu.u[0] = pack_bf2(e[2 * ks][0],     e[2 * ks][1]);
        pu.u[1] = pack_bf2(e[2 * ks][2],     e[2 * ks][3]);
        pu.u[2] = pack_bf2(e[2 * ks + 1][0], e[2 * ks + 1][1]);
        pu.u[3] = pack_bf2(e[2 * ks + 1][2], e[2 * ks + 1][3]);
        pfp[mf][ks] = pu.v;
      }
    }
    // stage tile 1 -> buf1; prefetch tile 2 -> regs
    char* Kn = (char*)Ks[1];
    char* Vn = (char*)Vs[1];
    *(u16x8*)(Kn + wof0) = kr;
    *(u16x8*)(Kn + wof1) = kr2;
    *(u16x8*)(Vn + wof0) = vr;
    *(u16x8*)(Vn + wof1) = vr2;
    kgp += (size_t)64 * LDQK;  vgp += 64;
    kr  = *(const u16x8*)kgp;
    kr2 = *(const u16x8*)(kgp + 8);
    vr  = *(const u16x8*)vgp;
    vr2 = *(const u16x8*)(vgp + 8);
    LGKM_BARRIER();
  }

  // ---- main loop t = 1..63: QK(t), PV(t-1)+l(t-1), softmax(t), stage(t+1).
  // unroll 2 so the vfp/pfp rotate is killed by copy-prop.
#pragma unroll 2
  for (int t = 1; t < 64; ++t) {
    const int cur = t & 1;
    const char* Kc = (const char*)Ks[cur];
    const char* Vc = (const char*)Vs[cur];

    // S^T(t) = K Q'^T
    f32x4 s4[2][4];
#pragma unroll
    for (int ni = 0; ni < 4; ni++) {
      const char* kb = Kc + (ni * 16 + ln) * 128;
      s16x8 kf0 = *(const s16x8*)(kb + ((q4 * 16)      ^ rswz));
      s16x8 kf1 = *(const s16x8*)(kb + ((q4 * 16 + 64) ^ rswz));
      __builtin_amdgcn_s_setprio(1);
#pragma unroll
      for (int mf = 0; mf < 2; ++mf) {
        f32x4 acc0 = __builtin_amdgcn_mfma_f32_16x16x32_bf16(kf0, qf[mf][0], fz, 0, 0, 0);
        s4[mf][ni] = __builtin_amdgcn_mfma_f32_16x16x32_bf16(kf1, qf[mf][1], acc0, 0, 0, 0);
      }
      __builtin_amdgcn_s_setprio(0);
    }

    // O += P(t-1) V(t-1); l += P(t-1) @ ones — register-only, independent
    // of s4(t): the scheduler interleaves these MFMAs with the exp2/pack
    // VALU below.
#pragma unroll
    for (int ks = 0; ks < 2; ++ks)
#pragma unroll
      for (int ni = 0; ni < 4; ni++)
#pragma unroll
        for (int mf = 0; mf < 2; ++mf)
          o[mf][ni] = __builtin_amdgcn_mfma_f32_16x16x32_bf16(pfp[mf][ks], vfp[ks][ni], o[mf][ni], 0, 0, 0);
#pragma unroll
    for (int mf = 0; mf < 2; ++mf)
#pragma unroll
      for (int ks = 0; ks < 2; ++ks)
        ol[mf] = __builtin_amdgcn_mfma_f32_16x16x32_bf16(pfp[mf][ks], onesf, ol[mf], 0, 0, 0);

    // vf(t) from LDS (independent of exp2 chain)
    s16x8 vfc[2][4];
#pragma unroll
    for (int ks = 0; ks < 2; ++ks)
#pragma unroll
      for (int ni = 0; ni < 4; ni++)
        vfc[ks][ni] = *(const s16x8*)(Vc + (ni * 16 + ln) * 128 +
                                      ((ks * 64 + q4 * 16) ^ rswz));

    // p(t) = exp2(s^T): pack into PV A-frags (kappa-aligned).
    s16x8 pfc[2][2];
#pragma unroll
    for (int mf = 0; mf < 2; ++mf) {
      float e[4][4];
#pragma unroll
      for (int ni = 0; ni < 4; ni++)
#pragma unroll
        for (int r = 0; r < 4; ++r)
          e[ni][r] = __builtin_amdgcn_exp2f(s4[mf][ni][r]);
#pragma unroll
      for (int ks = 0; ks < 2; ++ks) {
        union { s16x8 v; unsigned u[4]; } pu;
        pu.u[0] = pack_bf2(e[2 * ks][0],     e[2 * ks][1]);
        pu.u[1] = pack_bf2(e[2 * ks][2],     e[2 * ks][3]);
        pu.u[2] = pack_bf2(e[2 * ks + 1][0], e[2 * ks + 1][1]);
        pu.u[3] = pack_bf2(e[2 * ks + 1][2], e[2 * ks + 1][3]);
        pfc[mf][ks] = pu.v;
      }
    }

    // stage tile t+1 into other buffer; prefetch tile t+2
    if (t + 1 < 64) {
      char* Kn = (char*)Ks[cur ^ 1];
      char* Vn = (char*)Vs[cur ^ 1];
      *(u16x8*)(Kn + wof0) = kr;
      *(u16x8*)(Kn + wof1) = kr2;
      *(u16x8*)(Vn + wof0) = vr;
      *(u16x8*)(Vn + wof1) = vr2;
      if (t + 2 < 64) {
        kgp += (size_t)64 * LDQK;  vgp += 64;
        kr  = *(const u16x8*)kgp;
        kr2 = *(const u16x8*)(kgp + 8);
        vr  = *(const u16x8*)vgp;
        vr2 = *(const u16x8*)(vgp + 8);
      }
    }

    // rotate carried state (renamed away by the unroll-2 copy-prop)
#pragma unroll
    for (int ks = 0; ks < 2; ++ks)
#pragma unroll
      for (int ni = 0; ni < 4; ni++)
        vfp[ks][ni] = vfc[ks][ni];
#pragma unroll
    for (int mf = 0; mf < 2; ++mf)
#pragma unroll
      for (int ks = 0; ks < 2; ++ks)
        pfp[mf][ks] = pfc[mf][ks];

    // ds writes/reads drained; t+2 global prefetch rides across the barrier.
    LGKM_BARRIER();
  }

  // ---- epilogue: PV(63) + l(63)
  __builtin_amdgcn_s_setprio(1);
#pragma unroll
  for (int ks = 0; ks < 2; ++ks)
#pragma unroll
    for (int ni = 0; ni < 4; ni++)
#pragma unroll
      for (int mf = 0; mf < 2; ++mf)
        o[mf][ni] = __builtin_amdgcn_mfma_f32_16x16x32_bf16(pfp[mf][ks], vfp[ks][ni], o[mf][ni], 0, 0, 0);
#pragma unroll
  for (int mf = 0; mf < 2; ++mf)
#pragma unroll
    for (int ks = 0; ks < 2; ++ks)
      ol[mf] = __builtin_amdgcn_mfma_f32_16x16x32_bf16(pfp[mf][ks], onesf, ol[mf], 0, 0, 0);
  __builtin_amdgcn_s_setprio(0);

  // normalize: lane (q4,ln) holds l for q-rows q4*4+r in ol[mf][r] (every
  // ln replica identical) -> no cross-lane traffic at all.
#pragma unroll
  for (int mf = 0; mf < 2; ++mf)
#pragma unroll
    for (int r = 0; r < 4; ++r) {
      const float nv = 1.0f / ol[mf][r];
      const size_t row = rowbase + qrow0 + mf * 16 + q4 * 4 + r;
#pragma unroll
      for (int ni = 0; ni < 4; ni++)
        Oc[row * 512 + h * 64 + ni * 16 + ln] = f2bf(o[mf][ni][r] * nv);
    }
}

// out = Oc @ Wo^T : M=8192 N=512 K=512, tile 128x64, BK=64, swizzled (R19).
__global__ __launch_bounds__(256, 3) void gemm_out(
    const unsigned short* __restrict__ A,
    const unsigned short* __restrict__ Bt,
    float* __restrict__ C)
{
  __shared__ unsigned short As[128 * 64];
  __shared__ unsigned short Bs[64 * 64];
  const int tid  = threadIdx.x;
  const int wave = tid >> 6, lane = tid & 63;
  const int q4 = lane >> 4, ln = lane & 15;
  const size_t bm = (size_t)blockIdx.x * 128;
  const size_t bn = (size_t)blockIdx.y * 64;
  const int wm = (wave >> 1) * 64, wn = (wave & 1) * 32;
  f32x4 acc[4][2] = {};

  const int rlo  = lane >> 3;
  const int sbx  = ((lane & 7) << 4) ^ (rlo << 4);
  const int rswz = (ln & 7) << 4;

  const char* Asb = (const char*)A  + (size_t)(bm + wave * 32 + rlo) * 1024 + sbx;
  const char* Bsb = (const char*)Bt + (size_t)(bn + wave * 16 + rlo) * 1024 + sbx;
  char* Adst = (char*)As + wave * 4096;
  char* Bdst = (char*)Bs + wave * 2048;

  for (int kt = 0; kt < 512; kt += 64) {
    __syncthreads();
#pragma unroll
    for (int j = 0; j < 4; ++j)
      gll16(Asb + kt * 2 + j * 8192, Adst + j * 1024);
#pragma unroll
    for (int j = 0; j < 2; ++j)
      gll16(Bsb + kt * 2 + j * 8192, Bdst + j * 1024);
    __syncthreads();   // implies vmcnt(0): staged data visible
    s16x8 bfr[2][2];
#pragma unroll
    for (int ni = 0; ni < 2; ni++) {
      const char* bb = (char*)Bs + (wn + ni * 16 + ln) * 128;
      bfr[ni][0] = *(const s16x8*)(bb + ((q4 * 16)      ^ rswz));
      bfr[ni][1] = *(const s16x8*)(bb + ((q4 * 16 + 64) ^ rswz));
    }
#pragma unroll
    for (int mi = 0; mi < 4; mi++) {
      const char* ab = (char*)As + (wm + mi * 16 + ln) * 128;
      s16x8 af0 = *(const s16x8*)(ab + ((q4 * 16)      ^ rswz));
      s16x8 af1 = *(const s16x8*)(ab + ((q4 * 16 + 64) ^ rswz));
#pragma unroll
      for (int ni = 0; ni < 2; ni++) {
        acc[mi][ni] = __builtin_amdgcn_mfma_f32_16x16x32_bf16(
            af0, bfr[ni][0], acc[mi][ni], 0, 0, 0);
        acc[mi][ni] = __builtin_amdgcn_mfma_f32_16x16x32_bf16(
            af1, bfr[ni][1], acc[mi][ni], 0, 0, 0);
      }
    }
  }
#pragma unroll
  for (int mi = 0; mi < 4; mi++)
#pragma unroll
    for (int r = 0; r < 4; ++r) {
      size_t row = bm + wm + mi * 16 + q4 * 4 + r;
#pragma unroll
      for (int ni = 0; ni < 2; ni++)
        C[row * 512 + bn + wn + ni * 16 + ln] = acc[mi][ni][r];
    }
}

extern "C" void kernel_launch(void* const* d_in, const int* in_sizes, int n_in,
                              void* d_out, int out_size, void* d_ws, size_t ws_size,
                              hipStream_t stream) {
  const float* x  = (const float*)d_in[0];
  const float* Wq = (const float*)d_in[1];
  const float* Wk = (const float*)d_in[2];
  const float* Wv = (const float*)d_in[3];
  const float* Wo = (const float*)d_in[4];

  char* ws = (char*)d_ws;
  unsigned short* xb    = (unsigned short*)(ws);              //  8,388,608
  unsigned short* Wall  = (unsigned short*)(ws + 8388608);    //  2,097,152
  unsigned short* QKb   = (unsigned short*)(ws + 10485760);   // 16,777,216
  unsigned short* Vtb   = (unsigned short*)(ws + 27262976);   //  8,388,608
  unsigned short* Oc    = (unsigned short*)(ws + 35651584);   //  8,388,608

  const float C2 = 0.125f * 1.44269504088896f;  // 1/sqrt(64) * log2(e)

  hipLaunchKernelGGL(prep_kernel, dim3(1280), dim3(256), 0, stream,
                     x, Wq, Wk, Wv, Wo, xb, Wall, C2);
  hipLaunchKernelGGL(gemm_qkv, dim3(64, 12), dim3(256), 0, stream,
                     xb, Wall, QKb, Vtb);
  hipLaunchKernelGGL(attn_kernel, dim3(32, 8, 2), dim3(256), 0, stream,
                     QKb, Vtb, Oc);
  hipLaunchKernelGGL(gemm_out, dim3(64, 8), dim3(256), 0, stream,
                     Oc, Wall + 3 * 262144, (float*)d_out);
}